// Round 7
// baseline (412.396 us; speedup 1.0000x reference)
//
#include <hip/hip_runtime.h>
#include <cstdint>

typedef __bf16 bf16;
typedef __bf16 bf16x8 __attribute__((ext_vector_type(8)));
typedef __bf16 bf16x4 __attribute__((ext_vector_type(4)));
typedef float f32x4 __attribute__((ext_vector_type(4)));

#define DIMN 2048
#define SEQ  2048
#define NH   16
#define HD   128

// -------- async global->LDS 16B helper (m97 pattern) --------
__device__ __forceinline__ void gld_lds16(const bf16* g, bf16* l) {
    __builtin_amdgcn_global_load_lds(
        (const __attribute__((address_space(1))) void*)g,
        (__attribute__((address_space(3))) void*)l,
        16, 0, 0);
}

// -------- all fp32->bf16 casts in ONE launch --------
__global__ __launch_bounds__(256) void cast_all(
    const float* __restrict__ x,
    const float* __restrict__ wq, const float* __restrict__ wk,
    const float* __restrict__ wv, const float* __restrict__ wo,
    bf16* __restrict__ xb,
    bf16* __restrict__ wqb, bf16* __restrict__ wkb,
    bf16* __restrict__ wvb, bf16* __restrict__ wob)
{
    int id = blockIdx.x;
    const float* src; bf16* dst; int i;
    if (id < 8192) { src = x; dst = xb; i = id * 256 + threadIdx.x; }
    else {
        id -= 8192;
        int w = id >> 12; id &= 4095;
        src = (w == 0) ? wq : (w == 1) ? wk : (w == 2) ? wv : wo;
        dst = (w == 0) ? wqb : (w == 1) ? wkb : (w == 2) ? wvb : wob;
        i = id * 256 + threadIdx.x;
    }
    float4 v = ((const float4*)src)[i];
    bf16x4 o;
    o[0] = (bf16)v.x; o[1] = (bf16)v.y; o[2] = (bf16)v.z; o[3] = (bf16)v.w;
    ((bf16x4*)dst)[i] = o;
}

// -------- 128x128 m97-structure GEMM (845 TF on this shape; R3-verified).
// QKV: one z=3 dispatch. z=0: qb. z=1: kb. z=2: V^T via operand swap -> vt directly.
template<int OUT_F32>
__global__ __launch_bounds__(256) void gemm_bt(
    const bf16* __restrict__ A,
    const bf16* __restrict__ Bw0, const bf16* __restrict__ Bw1, const bf16* __restrict__ Bw2,
    const float* __restrict__ bias0, const float* __restrict__ bias1, const float* __restrict__ bias2,
    void* __restrict__ C0, void* __restrict__ C1, void* __restrict__ C2)
{
    const int K = DIMN, N = DIMN;
    const int vtm = (!OUT_F32) && (blockIdx.z == 2);   // V^T mode
    const bf16* Ap; const bf16* Bp; const float* bias; void* Cout;
    if (blockIdx.z == 0)      { Ap = A;   Bp = Bw0; bias = bias0; Cout = C0; }
    else if (blockIdx.z == 1) { Ap = A;   Bp = Bw1; bias = bias1; Cout = C1; }
    else                      { Ap = Bw2; Bp = A;   bias = bias2; Cout = C2; }

    __shared__ __attribute__((aligned(16))) bf16 As[128 * 64];
    __shared__ __attribute__((aligned(16))) bf16 Bs[128 * 64];

    const int t    = threadIdx.x;
    const int lane = t & 63, wave = t >> 6;
    const int l15  = lane & 15, quad = lane >> 4;
    const int wm   = (wave >> 1) * 64, wn = (wave & 1) * 64;
    const long bm = vtm ? (long)blockIdx.x * 128 : (long)blockIdx.y * 128;
    const long bn = vtm ? (long)blockIdx.y * 128 : (long)blockIdx.x * 128;

    const bf16* agp[4]; const bf16* bgp[4]; bf16* asd[4]; bf16* bsd[4];
#pragma unroll
    for (int it = 0; it < 4; it++) {
        int fs  = it * 256 + t;
        int row = fs >> 3;
        int gs  = (fs & 7) ^ (row & 7);
        agp[it] = Ap + (bm + row) * (long)K + gs * 8;
        bgp[it] = Bp + (bn + row) * (long)K + gs * 8;
        asd[it] = As + fs * 8;
        bsd[it] = Bs + fs * 8;
    }
    const int swl = l15 & 7;

    f32x4 acc[4][4] = {};

    for (int k0 = 0; k0 < K; k0 += 64) {
#pragma unroll
        for (int it = 0; it < 4; it++) {
            gld_lds16(agp[it] + k0, asd[it]);
            gld_lds16(bgp[it] + k0, bsd[it]);
        }
        __syncthreads();

#pragma unroll
        for (int ks2 = 0; ks2 < 2; ks2++) {
            const int sw = ((ks2 * 4 + quad) ^ swl) * 8;
            bf16x8 af[4], bfr[4];
#pragma unroll
            for (int i = 0; i < 4; i++)
                af[i] = *(const bf16x8*)(As + (wm + i * 16 + l15) * 64 + sw);
#pragma unroll
            for (int j = 0; j < 4; j++)
                bfr[j] = *(const bf16x8*)(Bs + (wn + j * 16 + l15) * 64 + sw);
#pragma unroll
            for (int i = 0; i < 4; i++)
#pragma unroll
                for (int j = 0; j < 4; j++)
                    acc[i][j] = __builtin_amdgcn_mfma_f32_16x16x32_bf16(af[i], bfr[j], acc[i][j], 0, 0, 0);
        }
        __syncthreads();
    }

    if (vtm) {
#pragma unroll
        for (int j = 0; j < 4; j++) {
            const long col = bn + wn + j * 16 + l15;
            const long cb = col >> 11, cs = col & (SEQ - 1);
#pragma unroll
            for (int i = 0; i < 4; i++) {
                const long m0 = bm + wm + i * 16 + quad * 4;
#pragma unroll
                for (int r = 0; r < 4; r++)
                    ((bf16*)Cout)[((cb * DIMN + m0 + r) * SEQ) + cs] =
                        (bf16)(acc[i][j][r] + bias[m0 + r]);
            }
        }
    } else {
#pragma unroll
        for (int j = 0; j < 4; j++) {
            const long col = bn + wn + j * 16 + l15;
            const float bv = bias[col];
#pragma unroll
            for (int i = 0; i < 4; i++) {
                const long row0 = bm + wm + i * 16 + quad * 4;
#pragma unroll
                for (int r = 0; r < 4; r++) {
                    float v = acc[i][j][r] + bv;
                    if (OUT_F32) ((float*)Cout)[(row0 + r) * N + col] = v;
                    else         ((bf16*)Cout)[(row0 + r) * N + col] = (bf16)v;
                }
            }
        }
    }
}

// -------- RMSNorm + RoPE on q,k --------
// Q pre-scale folds 1/sqrt(HD) * log2(e) so attention can use exp2f (bare v_exp_f32).
__global__ __launch_bounds__(256) void norm_prep(
    bf16* __restrict__ q, bf16* __restrict__ k,
    const float* __restrict__ gq, const float* __restrict__ gk,
    const float* __restrict__ freqs)
{
    const int id = blockIdx.x;
    const int t = threadIdx.x;
    const int qk  = id >> 12;
    const int row = id & 4095;                 // b*SEQ + s
    bf16* ptr = qk ? k : q;
    const float* g = qk ? gk : gq;
    const float osc = qk ? 1.0f : 0.12753138080219222f;  // (1/sqrt(128))*log2(e)
    const int s = row & (SEQ - 1);
    const int lane = t & 63, wave = t >> 6;

    bf16* base = ptr + (long)row * DIMN + t * 8;
    bf16x8 raw = *(const bf16x8*)base;
    float v[8]; float ss = 0.f;
#pragma unroll
    for (int j = 0; j < 8; j++) { v[j] = (float)raw[j]; ss += v[j] * v[j]; }
#pragma unroll
    for (int off = 32; off; off >>= 1) ss += __shfl_xor(ss, off, 64);
    __shared__ float red[4];
    if (lane == 0) red[wave] = ss;
    __syncthreads();
    float tot = red[0] + red[1] + red[2] + red[3];
    float rn = rsqrtf(tot * (1.0f / DIMN) + 1e-6f);

    const int e0 = t * 8;
    bf16x8 o;
#pragma unroll
    for (int pp = 0; pp < 4; pp++) {
        int e = e0 + pp * 2;
        float xr = v[pp * 2]     * rn * g[e];
        float xi = v[pp * 2 + 1] * rn * g[e + 1];
        int lc = (e >> 1) & 63;
        float cr = freqs[s * 128 + lc * 2];
        float ci = freqs[s * 128 + lc * 2 + 1];
        o[pp * 2]     = (bf16)((xr * cr - xi * ci) * osc);
        o[pp * 2 + 1] = (bf16)((xr * ci + xi * cr) * osc);
    }
    *(bf16x8*)base = o;
}

// ======== attention v5: in-register P (v4-verified exchange) + im=2 reuse ========
// 4 waves x 32 q-rows = 128 rows/block; grid (32 bh, 16 qt) = 512 blocks = 2/CU
// (LDS 64 KiB). Each kf/vfr b128 LDS read feeds 2 MFMAs (im reuse) -> 1 KB LDS
// reads per q-row per kt (v3 parity) at 2x v3's occupancy, zero bank conflicts.
__global__ __launch_bounds__(256, 2) void attention(
    const bf16* __restrict__ Q, const bf16* __restrict__ Kb,
    const bf16* __restrict__ Vt, bf16* __restrict__ O)
{
    __shared__ __attribute__((aligned(16))) bf16 Ksh[2][64 * 128];   // [kr][d], seg^=(kr&15)
    __shared__ __attribute__((aligned(16))) bf16 Vsh[2][128 * 64];   // [d][kr], seg^=(d&7)

    const int t = threadIdx.x;                 // 0..255
    const int lane = t & 63, w = t >> 6;       // 4 waves
    const int l15 = lane & 15, quad = lane >> 4;
    const int hi = quad >> 1;
    const int bh = blockIdx.x, b = bh >> 4, h = bh & 15;   // x = head: XCD-local K/V
    const int qt = blockIdx.y;                 // 0..15
    const long qrow0 = (long)b * SEQ + qt * 128 + w * 32;
    const bf16* qbase = Q  + qrow0 * DIMN + h * HD;
    const bf16* kbase = Kb + (long)b * SEQ * DIMN + h * HD;
    const bf16* vbase = Vt + (long)bh * HD * SEQ;

    // Q fragments resident (pre-scaled by norm_prep): B[m=l15][k=quad*8+j]
    bf16x8 qf[2][4];
#pragma unroll
    for (int im = 0; im < 2; im++)
#pragma unroll
        for (int kd = 0; kd < 4; kd++)
            qf[im][kd] = *(const bf16x8*)(qbase + (long)(im * 16 + l15) * DIMN + kd * 32 + quad * 8);

    // staging offsets: 4 passes x 256 threads cover K(64 rows x 16 segs) and V(128 x 8)
    long koff[4], voff[4];
#pragma unroll
    for (int it = 0; it < 4; it++) {
        int fs = it * 256 + t;
        int kr = fs >> 4, kp = fs & 15;
        koff[it] = (long)kr * DIMN + (kp ^ (kr & 15)) * 8;
        int dr = fs >> 3, vp = fs & 7;
        voff[it] = (long)dr * SEQ + (vp ^ (dr & 7)) * 8;
    }

    // bpermute byte indices for the two source quads of this lane (v4-verified)
    const int srcA = (((quad & 1) * 2) * 16 + l15) * 4;
    const int srcB = srcA + 64;

    f32x4 o_acc[2][8] = {};
    float Lt[2] = {0.f, 0.f};

#pragma unroll
    for (int it = 0; it < 4; it++) {
        gld_lds16(kbase + koff[it], &Ksh[0][(it * 256 + t) * 8]);
        gld_lds16(vbase + voff[it], &Vsh[0][(it * 256 + t) * 8]);
    }
    __syncthreads();

    for (int kt = 0; kt < 32; kt++) {
        const int cur = kt & 1;
        if (kt < 31) {
            const bf16* kg = kbase + (long)((kt + 1) * 64) * DIMN;
            const bf16* vg = vbase + (kt + 1) * 64;
#pragma unroll
            for (int it = 0; it < 4; it++) {
                gld_lds16(kg + koff[it], &Ksh[cur ^ 1][(it * 256 + t) * 8]);
                gld_lds16(vg + voff[it], &Vsh[cur ^ 1][(it * 256 + t) * 8]);
            }
        }
        const bf16* K0 = Ksh[cur];
        const bf16* V0 = Vsh[cur];

        // ---- S^T = K Q^T : st[jk][im] = P-pre[m][kr=jk*16+quad*4+r] ----
        f32x4 st[4][2] = {};
        __builtin_amdgcn_s_setprio(1);
#pragma unroll
        for (int jk = 0; jk < 4; jk++)
#pragma unroll
            for (int kd = 0; kd < 4; kd++) {
                bf16x8 kf = *(const bf16x8*)(K0 + (jk * 16 + l15) * 128 + (((kd * 4 + quad) ^ l15) & 15) * 8);
                st[jk][0] = __builtin_amdgcn_mfma_f32_16x16x32_bf16(kf, qf[0][kd], st[jk][0], 0, 0, 0);
                st[jk][1] = __builtin_amdgcn_mfma_f32_16x16x32_bf16(kf, qf[1][kd], st[jk][1], 0, 0, 0);
            }
        __builtin_amdgcn_s_setprio(0);

        // ---- exp2 + pack to bf16 words + L partial ----
        uint32_t pk0[2][4], pk1[2][4];
#pragma unroll
        for (int im = 0; im < 2; im++)
#pragma unroll
            for (int jk = 0; jk < 4; jk++) {
                float e0 = exp2f(st[jk][im][0]);
                float e1 = exp2f(st[jk][im][1]);
                float e2 = exp2f(st[jk][im][2]);
                float e3 = exp2f(st[jk][im][3]);
                Lt[im] += (e0 + e1) + (e2 + e3);
                uint32_t lo, hiw;
                asm("v_cvt_pk_bf16_f32 %0, %1, %2" : "=v"(lo)  : "v"(e0), "v"(e1));
                asm("v_cvt_pk_bf16_f32 %0, %1, %2" : "=v"(hiw) : "v"(e2), "v"(e3));
                pk0[im][jk] = lo; pk1[im][jk] = hiw;
            }

        // ---- in-register P redistribute (32 bpermute) + O += P V ----
        __builtin_amdgcn_s_setprio(1);
#pragma unroll
        for (int kd2 = 0; kd2 < 2; kd2++) {
            bf16x8 pa[2];
#pragma unroll
            for (int im = 0; im < 2; im++) {
                int a0 = __builtin_amdgcn_ds_bpermute(srcA, (int)pk0[im][kd2 * 2]);
                int a1 = __builtin_amdgcn_ds_bpermute(srcA, (int)pk0[im][kd2 * 2 + 1]);
                int b0 = __builtin_amdgcn_ds_bpermute(srcA, (int)pk1[im][kd2 * 2]);
                int b1 = __builtin_amdgcn_ds_bpermute(srcA, (int)pk1[im][kd2 * 2 + 1]);
                int c0 = __builtin_amdgcn_ds_bpermute(srcB, (int)pk0[im][kd2 * 2]);
                int c1 = __builtin_amdgcn_ds_bpermute(srcB, (int)pk0[im][kd2 * 2 + 1]);
                int d0 = __builtin_amdgcn_ds_bpermute(srcB, (int)pk1[im][kd2 * 2]);
                int d1 = __builtin_amdgcn_ds_bpermute(srcB, (int)pk1[im][kd2 * 2 + 1]);
                union { uint32_t u[4]; bf16x8 v; } pu;
                pu.u[0] = hi ? (uint32_t)a1 : (uint32_t)a0;   // j=0,1  (pk0 @ srcA)
                pu.u[1] = hi ? (uint32_t)b1 : (uint32_t)b0;   // j=2,3  (pk1 @ srcA)
                pu.u[2] = hi ? (uint32_t)c1 : (uint32_t)c0;   // j=4,5  (pk0 @ srcB)
                pu.u[3] = hi ? (uint32_t)d1 : (uint32_t)d0;   // j=6,7  (pk1 @ srcB)
                pa[im] = pu.v;
            }
#pragma unroll
            for (int dj = 0; dj < 8; dj++) {
                bf16x8 vfr = *(const bf16x8*)(V0 + (dj * 16 + l15) * 64 + (((kd2 * 4 + quad) ^ l15) & 7) * 8);
                o_acc[0][dj] = __builtin_amdgcn_mfma_f32_16x16x32_bf16(pa[0], vfr, o_acc[0][dj], 0, 0, 0);
                o_acc[1][dj] = __builtin_amdgcn_mfma_f32_16x16x32_bf16(pa[1], vfr, o_acc[1][dj], 0, 0, 0);
            }
        }
        __builtin_amdgcn_s_setprio(0);
        __syncthreads();   // drains this iter's prefetch (overlapped) + releases cur buffer
    }

    // L: butterfly over the 4 quads sharing l15 -> all lanes hold L[m=l15]
#pragma unroll
    for (int im = 0; im < 2; im++) {
        Lt[im] += __shfl_xor(Lt[im], 16, 64);
        Lt[im] += __shfl_xor(Lt[im], 32, 64);
    }

    // normalize + write (aliases Q buffer: block (qt,bh) writes only rows/cols it alone read)
#pragma unroll
    for (int im = 0; im < 2; im++)
#pragma unroll
        for (int r = 0; r < 4; r++) {
            float Lr = __shfl(Lt[im], quad * 4 + r, 64);   // L for row m = quad*4+r
            float inv = 1.0f / Lr;
            long orow = qrow0 + im * 16 + quad * 4 + r;
#pragma unroll
            for (int dj = 0; dj < 8; dj++)
                O[orow * DIMN + h * HD + dj * 16 + l15] = (bf16)(o_acc[im][dj][r] * inv);
        }
}

extern "C" void kernel_launch(void* const* d_in, const int* in_sizes, int n_in,
                              void* d_out, int out_size, void* d_ws, size_t ws_size,
                              hipStream_t stream) {
    const float* x     = (const float*)d_in[0];
    const float* freqs = (const float*)d_in[1];
    const float* wq    = (const float*)d_in[2];
    const float* bq    = (const float*)d_in[3];
    const float* wk    = (const float*)d_in[4];
    const float* bk    = (const float*)d_in[5];
    const float* wv    = (const float*)d_in[6];
    const float* bv    = (const float*)d_in[7];
    const float* wo    = (const float*)d_in[8];
    const float* bo    = (const float*)d_in[9];
    const float* gq    = (const float*)d_in[10];
    const float* gk    = (const float*)d_in[11];
    float* out = (float*)d_out;

    const size_t MAT  = (size_t)4096 * 2048 * 2;   // 16 MiB
    const size_t WMAT = (size_t)2048 * 2048 * 2;   // 8 MiB
    char* p = (char*)d_ws;
    bf16* xb  = (bf16*)p; p += MAT;
    bf16* wqb = (bf16*)p; p += WMAT;
    bf16* wkb = (bf16*)p; p += WMAT;
    bf16* wvb = (bf16*)p; p += WMAT;
    bf16* wob = (bf16*)p; p += WMAT;
    bf16* qb  = (bf16*)p; p += MAT;
    bf16* kb  = (bf16*)p; p += MAT;
    bf16* vt  = (bf16*)p; p += MAT;
    bf16* attn = qb;   // alias (safe: per-block exclusive row/col regions)

    cast_all<<<24576, 256, 0, stream>>>(x, wq, wk, wv, wo, xb, wqb, wkb, wvb, wob);

    // Q, K, V^T in one dispatch (z=2 writes vt directly via operand swap)
    gemm_bt<0><<<dim3(16, 32, 3), 256, 0, stream>>>(xb, wqb, wkb, wvb,
                                                    bq, bk, bv, qb, kb, vt);

    norm_prep<<<8192, 256, 0, stream>>>(qb, kb, gq, gk, freqs);
    attention<<<dim3(32, 16), 256, 0, stream>>>(qb, kb, vt, attn);
    gemm_bt<1><<<dim3(16, 32, 1), 256, 0, stream>>>(attn, wob, wob, wob,
                                                    bo, bo, bo, out, out, out);
}

// Round 8
// 405.431 us; speedup vs baseline: 1.0172x; 1.0172x over previous
//
#include <hip/hip_runtime.h>
#include <cstdint>

typedef __bf16 bf16;
typedef __bf16 bf16x8 __attribute__((ext_vector_type(8)));
typedef __bf16 bf16x4 __attribute__((ext_vector_type(4)));
typedef float f32x4 __attribute__((ext_vector_type(4)));
typedef float f32x16 __attribute__((ext_vector_type(16)));

#define DIMN 2048
#define SEQ  2048
#define NH   16
#define HD   128

// -------- async global->LDS 16B helper (m97 pattern) --------
__device__ __forceinline__ void gld_lds16(const bf16* g, bf16* l) {
    __builtin_amdgcn_global_load_lds(
        (const __attribute__((address_space(1))) void*)g,
        (__attribute__((address_space(3))) void*)l,
        16, 0, 0);
}

// -------- all fp32->bf16 casts in ONE launch --------
__global__ __launch_bounds__(256) void cast_all(
    const float* __restrict__ x,
    const float* __restrict__ wq, const float* __restrict__ wk,
    const float* __restrict__ wv, const float* __restrict__ wo,
    bf16* __restrict__ xb,
    bf16* __restrict__ wqb, bf16* __restrict__ wkb,
    bf16* __restrict__ wvb, bf16* __restrict__ wob)
{
    int id = blockIdx.x;
    const float* src; bf16* dst; int i;
    if (id < 8192) { src = x; dst = xb; i = id * 256 + threadIdx.x; }
    else {
        id -= 8192;
        int w = id >> 12; id &= 4095;
        src = (w == 0) ? wq : (w == 1) ? wk : (w == 2) ? wv : wo;
        dst = (w == 0) ? wqb : (w == 1) ? wkb : (w == 2) ? wvb : wob;
        i = id * 256 + threadIdx.x;
    }
    float4 v = ((const float4*)src)[i];
    bf16x4 o;
    o[0] = (bf16)v.x; o[1] = (bf16)v.y; o[2] = (bf16)v.z; o[3] = (bf16)v.w;
    ((bf16x4*)dst)[i] = o;
}

// -------- 128x128 m97-structure GEMM (845 TF on this shape; R3-verified math).
// Split into one dispatch per output so attention surfaces in rocprof top-5.
// VTM=1: C[n][s] = A(wv) . Bw(x)^T + bias-by-row -> V^T written directly.
template<int OUT_F32, int VTM>
__global__ __launch_bounds__(256) void gemm_bt(
    const bf16* __restrict__ A, const bf16* __restrict__ Bw,
    const float* __restrict__ bias, void* __restrict__ Cout)
{
    const int K = DIMN, N = DIMN;

    __shared__ __attribute__((aligned(16))) bf16 As[128 * 64];
    __shared__ __attribute__((aligned(16))) bf16 Bs[128 * 64];

    const int t    = threadIdx.x;
    const int lane = t & 63, wave = t >> 6;
    const int l15  = lane & 15, quad = lane >> 4;
    const int wm   = (wave >> 1) * 64, wn = (wave & 1) * 64;
    const long bm = VTM ? (long)blockIdx.x * 128 : (long)blockIdx.y * 128;
    const long bn = VTM ? (long)blockIdx.y * 128 : (long)blockIdx.x * 128;

    const bf16* agp[4]; const bf16* bgp[4]; bf16* asd[4]; bf16* bsd[4];
#pragma unroll
    for (int it = 0; it < 4; it++) {
        int fs  = it * 256 + t;
        int row = fs >> 3;
        int gs  = (fs & 7) ^ (row & 7);
        agp[it] = A  + (bm + row) * (long)K + gs * 8;
        bgp[it] = Bw + (bn + row) * (long)K + gs * 8;
        asd[it] = As + fs * 8;
        bsd[it] = Bs + fs * 8;
    }
    const int swl = l15 & 7;

    f32x4 acc[4][4] = {};

    for (int k0 = 0; k0 < K; k0 += 64) {
#pragma unroll
        for (int it = 0; it < 4; it++) {
            gld_lds16(agp[it] + k0, asd[it]);
            gld_lds16(bgp[it] + k0, bsd[it]);
        }
        __syncthreads();

#pragma unroll
        for (int ks2 = 0; ks2 < 2; ks2++) {
            const int sw = ((ks2 * 4 + quad) ^ swl) * 8;
            bf16x8 af[4], bfr[4];
#pragma unroll
            for (int i = 0; i < 4; i++)
                af[i] = *(const bf16x8*)(As + (wm + i * 16 + l15) * 64 + sw);
#pragma unroll
            for (int j = 0; j < 4; j++)
                bfr[j] = *(const bf16x8*)(Bs + (wn + j * 16 + l15) * 64 + sw);
#pragma unroll
            for (int i = 0; i < 4; i++)
#pragma unroll
                for (int j = 0; j < 4; j++)
                    acc[i][j] = __builtin_amdgcn_mfma_f32_16x16x32_bf16(af[i], bfr[j], acc[i][j], 0, 0, 0);
        }
        __syncthreads();
    }

    if (VTM) {
#pragma unroll
        for (int j = 0; j < 4; j++) {
            const long col = bn + wn + j * 16 + l15;
            const long cb = col >> 11, cs = col & (SEQ - 1);
#pragma unroll
            for (int i = 0; i < 4; i++) {
                const long m0 = bm + wm + i * 16 + quad * 4;
#pragma unroll
                for (int r = 0; r < 4; r++)
                    ((bf16*)Cout)[((cb * DIMN + m0 + r) * SEQ) + cs] =
                        (bf16)(acc[i][j][r] + bias[m0 + r]);
            }
        }
    } else {
#pragma unroll
        for (int j = 0; j < 4; j++) {
            const long col = bn + wn + j * 16 + l15;
            const float bv = bias[col];
#pragma unroll
            for (int i = 0; i < 4; i++) {
                const long row0 = bm + wm + i * 16 + quad * 4;
#pragma unroll
                for (int r = 0; r < 4; r++) {
                    float v = acc[i][j][r] + bv;
                    if (OUT_F32) ((float*)Cout)[(row0 + r) * N + col] = v;
                    else         ((bf16*)Cout)[(row0 + r) * N + col] = (bf16)v;
                }
            }
        }
    }
}

// -------- RMSNorm + RoPE on q,k --------
// Q pre-scale folds 1/sqrt(HD) * log2(e) so attention can use exp2f (bare v_exp_f32).
__global__ __launch_bounds__(256) void norm_prep(
    bf16* __restrict__ q, bf16* __restrict__ k,
    const float* __restrict__ gq, const float* __restrict__ gk,
    const float* __restrict__ freqs)
{
    const int id = blockIdx.x;
    const int t = threadIdx.x;
    const int qk  = id >> 12;
    const int row = id & 4095;                 // b*SEQ + s
    bf16* ptr = qk ? k : q;
    const float* g = qk ? gk : gq;
    const float osc = qk ? 1.0f : 0.12753138080219222f;  // (1/sqrt(128))*log2(e)
    const int s = row & (SEQ - 1);
    const int lane = t & 63, wave = t >> 6;

    bf16* base = ptr + (long)row * DIMN + t * 8;
    bf16x8 raw = *(const bf16x8*)base;
    float v[8]; float ss = 0.f;
#pragma unroll
    for (int j = 0; j < 8; j++) { v[j] = (float)raw[j]; ss += v[j] * v[j]; }
#pragma unroll
    for (int off = 32; off; off >>= 1) ss += __shfl_xor(ss, off, 64);
    __shared__ float red[4];
    if (lane == 0) red[wave] = ss;
    __syncthreads();
    float tot = red[0] + red[1] + red[2] + red[3];
    float rn = rsqrtf(tot * (1.0f / DIMN) + 1e-6f);

    const int e0 = t * 8;
    bf16x8 o;
#pragma unroll
    for (int pp = 0; pp < 4; pp++) {
        int e = e0 + pp * 2;
        float xr = v[pp * 2]     * rn * g[e];
        float xi = v[pp * 2 + 1] * rn * g[e + 1];
        int lc = (e >> 1) & 63;
        float cr = freqs[s * 128 + lc * 2];
        float ci = freqs[s * 128 + lc * 2 + 1];
        o[pp * 2]     = (bf16)((xr * cr - xi * ci) * osc);
        o[pp * 2 + 1] = (bf16)((xr * ci + xi * cr) * osc);
    }
    *(bf16x8*)base = o;
}

// ======== attention v6: 32x32 MFMA, P exchange fully on VALU ========
// 8 waves x 32 rows = 256 rows/block (best staging amortization), grid (32,8)=256,
// LDS 64 KiB (K/V dbuf only — no Psh). S^T = K.Q^T via mfma_32x32x16: lane owns
// P column m=l&31 in regs (C/D: col=l&31, row=(reg&3)+8*(reg>>2)+4*hi).
// PV A-frag assembled per 16-k-step with 4 v_cvt_pk_bf16_f32 + 2 v_permlane32_swap
// (VALU only): target word c' sources reg (2c'&3)+8*(k&1)+4*hi_t at half hi_s=c'>>1
// -> swap(W0,W2),swap(W1,W3) yields [X02,X13,Y02,Y13] uniformly for all lanes.
__global__ __launch_bounds__(512, 2) void attention(
    const bf16* __restrict__ Q, const bf16* __restrict__ Kb,
    const bf16* __restrict__ Vt, bf16* __restrict__ O)
{
    __shared__ __attribute__((aligned(16))) bf16 Ksh[2][64 * 128];   // [kr][d], seg^=(kr&15)
    __shared__ __attribute__((aligned(16))) bf16 Vsh[2][128 * 64];   // [d][kr], seg^=(d&7)

    const int t = threadIdx.x;                 // 0..511
    const int lane = t & 63, w = t >> 6;       // 8 waves
    const int l31 = lane & 31, hi = lane >> 5;
    const int bh = blockIdx.x, b = bh >> 4, h = bh & 15;   // x = head: XCD-local K/V
    const int qt = blockIdx.y;                 // 0..7
    const long qrow0 = (long)b * SEQ + qt * 256 + w * 32;
    const bf16* qbase = Q  + qrow0 * DIMN + h * HD;
    const bf16* kbase = Kb + (long)b * SEQ * DIMN + h * HD;
    const bf16* vbase = Vt + (long)bh * HD * SEQ;

    // Q B-frag (32x32x16): n=m=l31, k = d = kd*16 + hi*8 + j  (pre-scaled by norm_prep)
    bf16x8 qf[8];
#pragma unroll
    for (int kd = 0; kd < 8; kd++)
        qf[kd] = *(const bf16x8*)(qbase + (long)l31 * DIMN + kd * 16 + hi * 8);

    // staging offsets (v3-verified): 2 passes x 512 threads cover K(64x16segs), V(128x8)
    long koff[2], voff[2];
#pragma unroll
    for (int it = 0; it < 2; it++) {
        int fs = it * 512 + t;
        int kr = fs >> 4, kp = fs & 15;
        koff[it] = (long)kr * DIMN + (kp ^ (kr & 15)) * 8;
        int dr = fs >> 3, vp = fs & 7;
        voff[it] = (long)dr * SEQ + (vp ^ (dr & 7)) * 8;
    }

    f32x16 o_acc[4] = {};
    float Lt = 0.f;

#pragma unroll
    for (int it = 0; it < 2; it++) {
        gld_lds16(kbase + koff[it], &Ksh[0][(it * 512 + t) * 8]);
        gld_lds16(vbase + voff[it], &Vsh[0][(it * 512 + t) * 8]);
    }
    __syncthreads();

    for (int kt = 0; kt < 32; kt++) {
        const int cur = kt & 1;
        if (kt < 31) {
            const bf16* kg = kbase + (long)((kt + 1) * 64) * DIMN;
            const bf16* vg = vbase + (kt + 1) * 64;
#pragma unroll
            for (int it = 0; it < 2; it++) {
                gld_lds16(kg + koff[it], &Ksh[cur ^ 1][(it * 512 + t) * 8]);
                gld_lds16(vg + voff[it], &Vsh[cur ^ 1][(it * 512 + t) * 8]);
            }
        }
        const bf16* K0 = Ksh[cur];
        const bf16* V0 = Vsh[cur];

        // ---- S^T = K Q^T : A-frag = K[kr=jk*32+l31][d=kd*16+hi*8+j] ----
        f32x16 st0 = {}, st1 = {};
        __builtin_amdgcn_s_setprio(1);
#pragma unroll
        for (int kd = 0; kd < 8; kd++) {
            const int sg = ((kd * 2 + hi) ^ (lane & 15)) * 8;
            bf16x8 kf0 = *(const bf16x8*)(K0 + (l31)      * 128 + sg);
            bf16x8 kf1 = *(const bf16x8*)(K0 + (32 + l31) * 128 + sg);
            st0 = __builtin_amdgcn_mfma_f32_32x32x16_bf16(kf0, qf[kd], st0, 0, 0, 0);
            st1 = __builtin_amdgcn_mfma_f32_32x32x16_bf16(kf1, qf[kd], st1, 0, 0, 0);
        }
        __builtin_amdgcn_s_setprio(0);

        // ---- exp2 in place + per-lane partial L ----
        float part = 0.f;
#pragma unroll
        for (int r = 0; r < 16; r++) {
            st0[r] = exp2f(st0[r]); part += st0[r];
            st1[r] = exp2f(st1[r]); part += st1[r];
        }
        Lt += part;

        // ---- per 16-k-step: assemble P A-frag (VALU) and accumulate PV ----
        __builtin_amdgcn_s_setprio(1);
#pragma unroll
        for (int k = 0; k < 4; k++) {
            const int base = 8 * (k & 1);
            float e0, e1, e2, e3, e4, e5, e6, e7;
            if (k < 2) {
                e0 = st0[base]; e1 = st0[base+1]; e2 = st0[base+2]; e3 = st0[base+3];
                e4 = st0[base+4]; e5 = st0[base+5]; e6 = st0[base+6]; e7 = st0[base+7];
            } else {
                e0 = st1[base]; e1 = st1[base+1]; e2 = st1[base+2]; e3 = st1[base+3];
                e4 = st1[base+4]; e5 = st1[base+5]; e6 = st1[base+6]; e7 = st1[base+7];
            }
            uint32_t W0, W1, W2, W3;
            asm("v_cvt_pk_bf16_f32 %0, %1, %2" : "=v"(W0) : "v"(e0), "v"(e1));
            asm("v_cvt_pk_bf16_f32 %0, %1, %2" : "=v"(W1) : "v"(e2), "v"(e3));
            asm("v_cvt_pk_bf16_f32 %0, %1, %2" : "=v"(W2) : "v"(e4), "v"(e5));
            asm("v_cvt_pk_bf16_f32 %0, %1, %2" : "=v"(W3) : "v"(e6), "v"(e7));
            // swap: W0' = [W0.lo|W2.lo] (word0), W2' = [W0.hi|W2.hi] (word2); same for 1,3
            asm volatile("v_permlane32_swap_b32 %0, %1" : "+v"(W0), "+v"(W2));
            asm volatile("v_permlane32_swap_b32 %0, %1" : "+v"(W1), "+v"(W3));
            union { uint32_t u[4]; bf16x8 v; } pu;
            pu.u[0] = W0; pu.u[1] = W1; pu.u[2] = W2; pu.u[3] = W3;
            const bf16x8 pa = pu.v;
#pragma unroll
            for (int dj = 0; dj < 4; dj++) {
                const bf16x8 vfr = *(const bf16x8*)(V0 + (dj * 32 + l31) * 64 +
                                                    (((2 * k + hi) ^ (lane & 7)) * 8));
                o_acc[dj] = __builtin_amdgcn_mfma_f32_32x32x16_bf16(pa, vfr, o_acc[dj], 0, 0, 0);
            }
        }
        __builtin_amdgcn_s_setprio(0);
        __syncthreads();   // drains this iter's prefetch (overlapped) + releases cur buffer
    }

    // L: lane holds sum over its hi-half of kr for column m=l31; add the other half
    float Lfull = Lt + __shfl_xor(Lt, 32, 64);   // all lanes: L[m = l31]

    float inv_[16];
#pragma unroll
    for (int r = 0; r < 16; r++) {
        int mr = (r & 3) + 8 * (r >> 2) + 4 * hi;
        inv_[r] = 1.0f / __shfl(Lfull, mr, 64);
    }

    // write: o_acc[dj][r] is O[m = (r&3)+8*(r>>2)+4*hi][d = dj*32+l31]
#pragma unroll
    for (int dj = 0; dj < 4; dj++)
#pragma unroll
        for (int r = 0; r < 16; r++) {
            int mr = (r & 3) + 8 * (r >> 2) + 4 * hi;
            long orow = qrow0 + mr;
            O[orow * DIMN + h * HD + dj * 32 + l31] = (bf16)(o_acc[dj][r] * inv_[r]);
        }
}

extern "C" void kernel_launch(void* const* d_in, const int* in_sizes, int n_in,
                              void* d_out, int out_size, void* d_ws, size_t ws_size,
                              hipStream_t stream) {
    const float* x     = (const float*)d_in[0];
    const float* freqs = (const float*)d_in[1];
    const float* wq    = (const float*)d_in[2];
    const float* bq    = (const float*)d_in[3];
    const float* wk    = (const float*)d_in[4];
    const float* bk    = (const float*)d_in[5];
    const float* wv    = (const float*)d_in[6];
    const float* bv    = (const float*)d_in[7];
    const float* wo    = (const float*)d_in[8];
    const float* bo    = (const float*)d_in[9];
    const float* gq    = (const float*)d_in[10];
    const float* gk    = (const float*)d_in[11];
    float* out = (float*)d_out;

    const size_t MAT  = (size_t)4096 * 2048 * 2;   // 16 MiB
    const size_t WMAT = (size_t)2048 * 2048 * 2;   // 8 MiB
    char* p = (char*)d_ws;
    bf16* xb  = (bf16*)p; p += MAT;
    bf16* wqb = (bf16*)p; p += WMAT;
    bf16* wkb = (bf16*)p; p += WMAT;
    bf16* wvb = (bf16*)p; p += WMAT;
    bf16* wob = (bf16*)p; p += WMAT;
    bf16* qb  = (bf16*)p; p += MAT;
    bf16* kb  = (bf16*)p; p += MAT;
    bf16* vt  = (bf16*)p; p += MAT;
    bf16* attn = qb;   // alias (safe: per-block exclusive row/col regions)

    cast_all<<<24576, 256, 0, stream>>>(x, wq, wk, wv, wo, xb, wqb, wkb, wvb, wob);

    // QKV as three dispatches (time-neutral per R2; surfaces attention in top-5)
    gemm_bt<0, 0><<<dim3(16, 32), 256, 0, stream>>>(xb, wqb, bq, qb);
    gemm_bt<0, 0><<<dim3(16, 32), 256, 0, stream>>>(xb, wkb, bk, kb);
    gemm_bt<0, 1><<<dim3(16, 32), 256, 0, stream>>>(wvb, xb, bv, vt);  // V^T direct

    norm_prep<<<8192, 256, 0, stream>>>(qb, kb, gq, gk, freqs);
    attention<<<dim3(32, 8), 512, 0, stream>>>(qb, kb, vt, attn);
    gemm_bt<1, 0><<<dim3(16, 32), 256, 0, stream>>>(attn, wob, bo, out);
}